// Round 6
// baseline (423.088 us; speedup 1.0000x reference)
//
#include <hip/hip_runtime.h>
#include <hip/hip_bf16.h>

typedef unsigned long long u64;

#define H_SZ 4096
#define NBITS 16
#define NFEAT 128
#define NCLS 10
#define THETA 8

// Bit convention: for chunk c of 256 positions, word (c,j) j=0..3 has bit
// i <-> position p = c*256 + 4*i + j (what per-component ballots of a
// lane-major float4 load produce). Acts packed identically. Mask words for
// chunk c: masks[c*8 + j*2 + t], t=0 pos / t=1 neg.

// ---------------------------------------------------------------------------
// Encode: x[64,128] -> thermometer bits, actp0[(c*4+j)*64 + b], c=0..7.
// ---------------------------------------------------------------------------
__global__ void encode_kernel(const float* __restrict__ x, u64* __restrict__ actp0) {
    int idx = blockIdx.x * blockDim.x + threadIdx.x;   // 0..2047
    if (idx >= 32 * 64) return;
    int wword = idx >> 6;        // 0..31
    int b = idx & 63;
    int c = wword >> 2, j = wword & 3;
    u64 word = 0;
    for (int i = 0; i < 64; i++) {
        int p = c * 256 + 4 * i + j;
        int f = p >> 4, t = p & 15;
        float thr = (t + 1.0f) / (NBITS + 1.0f);   // identical fp32 math to ref
        if (x[b * NFEAT + f] >= thr) word |= (1ULL << i);
    }
    actp0[wword * 64 + b] = word;
}

// ---------------------------------------------------------------------------
// Combined streaming kernel — ALL 320 MB of weights in one parallel phase.
//   blocks    0..511 : fused layer-0 (W0, 64 MB) -> ballots   [needs actp0]
//   blocks 512..1535 : convert W1 (128 MB) -> mask1 (8 MB)    [independent]
//   blocks 1536..2559: convert W2 (128 MB) -> mask2 (8 MB)    [independent]
// Layer-0 path: wave = 4 rows (32 KB contiguous), A/B register double-buffer
// of 8 KB groups, ballots -> sign masks, popcount vs acts in LDS (lane=batch).
// Convert path: wave = 32 chunks (32 KB), same pipeline, lanes 0..7 store the
// 8 mask words per chunk.
// ---------------------------------------------------------------------------
__global__ __launch_bounds__(256, 4) void stream_kernel(const float* __restrict__ W0,
                                                        const float* __restrict__ W1,
                                                        const float* __restrict__ W2,
                                                        const u64* __restrict__ actp0,
                                                        u64* __restrict__ ballots,
                                                        u64* __restrict__ mask1,
                                                        u64* __restrict__ mask2) {
    constexpr int G = 8;                  // chunks per pipeline group (8 KB)
    __shared__ u64 lds[2048];             // 16 KB acts (layer-0 blocks only)
    int tid = threadIdx.x;
    int lane = tid & 63;
    int warp = tid >> 6;
    int bid = blockIdx.x;

    if (bid < 512) {
        // ---------------- fused layer-0: NCH=8, 4 rows/wave ----------------
        for (int i = tid; i < 2048; i += 256) lds[i] = actp0[i];
        __syncthreads();

        int wave = bid * 4 + warp;            // 0..2047
        int wid0 = wave * 4;                  // first (h,s) row
        const float4* base = (const float4*)(W0 + (size_t)wid0 * 2048) + lane;

        float4 A[G], B[G];
        #pragma unroll
        for (int k = 0; k < G; k++) A[k] = base[k * 64];

        #pragma unroll
        for (int g = 0; g < 4; g++) {         // one group == one row (8 chunks)
            float4* cur = (g & 1) ? B : A;
            float4* nxt = (g & 1) ? A : B;
            if (g + 1 < 4) {
                #pragma unroll
                for (int k = 0; k < G; k++) nxt[k] = base[((g + 1) * G + k) * 64];
            }
            int z = 0;
            #pragma unroll
            for (int k = 0; k < G; k++) {     // chunk within row
                float4 v = cur[k];
                u64 p0 = __ballot(v.x > 0.0f);
                u64 n0 = __ballot(v.x < 0.0f);
                u64 p1 = __ballot(v.y > 0.0f);
                u64 n1 = __ballot(v.y < 0.0f);
                u64 p2 = __ballot(v.z > 0.0f);
                u64 n2 = __ballot(v.z < 0.0f);
                u64 p3 = __ballot(v.w > 0.0f);
                u64 n3 = __ballot(v.w < 0.0f);
                u64 a0 = lds[(k * 4 + 0) * 64 + lane];
                u64 a1 = lds[(k * 4 + 1) * 64 + lane];
                u64 a2 = lds[(k * 4 + 2) * 64 + lane];
                u64 a3 = lds[(k * 4 + 3) * 64 + lane];
                z += __builtin_popcountll(a0 & p0) - __builtin_popcountll(a0 & n0)
                   + __builtin_popcountll(a1 & p1) - __builtin_popcountll(a1 & n1)
                   + __builtin_popcountll(a2 & p2) - __builtin_popcountll(a2 & n2)
                   + __builtin_popcountll(a3 & p3) - __builtin_popcountll(a3 & n3);
            }
            u64 fz = __ballot(z >= THETA);
            if (lane == 0) ballots[wid0 + g] = fz;
        }
    } else {
        // ---------------- pure streaming convert: 32 chunks/wave ----------------
        const float* Wsrc = (bid < 1536) ? W1 : W2;
        u64* masks = (bid < 1536) ? mask1 : mask2;
        int wave = ((bid < 1536) ? (bid - 512) : (bid - 1536)) * 4 + warp;  // 0..4095
        size_t c0 = (size_t)wave * 32;
        const float4* base = (const float4*)Wsrc + c0 * 64 + lane;

        float4 A[G], B[G];
        #pragma unroll
        for (int k = 0; k < G; k++) A[k] = base[k * 64];

        #pragma unroll
        for (int g = 0; g < 4; g++) {
            float4* cur = (g & 1) ? B : A;
            float4* nxt = (g & 1) ? A : B;
            if (g + 1 < 4) {
                #pragma unroll
                for (int k = 0; k < G; k++) nxt[k] = base[((g + 1) * G + k) * 64];
            }
            #pragma unroll
            for (int k = 0; k < G; k++) {
                float4 v = cur[k];
                u64 m0 = __ballot(v.x > 0.0f);
                u64 m1 = __ballot(v.x < 0.0f);
                u64 m2 = __ballot(v.y > 0.0f);
                u64 m3 = __ballot(v.y < 0.0f);
                u64 m4 = __ballot(v.z > 0.0f);
                u64 m5 = __ballot(v.z < 0.0f);
                u64 m6 = __ballot(v.w > 0.0f);
                u64 m7 = __ballot(v.w < 0.0f);
                u64 w = m0;
                w = (lane == 1) ? m1 : w;
                w = (lane == 2) ? m2 : w;
                w = (lane == 3) ? m3 : w;
                w = (lane == 4) ? m4 : w;
                w = (lane == 5) ? m5 : w;
                w = (lane == 6) ? m6 : w;
                w = (lane == 7) ? m7 : w;
                if (lane < 8) masks[(c0 + g * G + k) * 8 + lane] = w;
            }
        }
    }
}

// ---------------------------------------------------------------------------
// Mask layer (layers 1,2): block = 16 rows. Stage 16 KB of masks + 32 KB acts
// into LDS with lane-parallel loads, then wave (lane = batch) walks its 4 rows
// with wave-uniform LDS broadcast reads of mask words (conflict-free).
// grid: 512 blocks x 256 thr.
// ---------------------------------------------------------------------------
__global__ __launch_bounds__(256) void mask_layer_kernel(const u64* __restrict__ masks,
                                                         const u64* __restrict__ actp,
                                                         u64* __restrict__ ballots) {
    __shared__ u64 am[4096];     // 32 KB acts: [(c*4+j)*64 + b]
    __shared__ u64 mm[2048];     // 16 KB masks: [local_row*128 + cc*8 + j*2 + t]
    int tid = threadIdx.x;
    int r0 = blockIdx.x * 16;
    for (int i = tid; i < 4096; i += 256) am[i] = actp[i];
    for (int i = tid; i < 2048; i += 256) mm[i] = masks[(size_t)r0 * 128 + i];
    __syncthreads();

    int lane = tid & 63;
    int warp = tid >> 6;
    #pragma unroll
    for (int rr = 0; rr < 4; rr++) {
        int local = warp * 4 + rr;
        int z = 0;
        #pragma unroll
        for (int c = 0; c < 16; c++) {
            #pragma unroll
            for (int j = 0; j < 4; j++) {
                u64 p = mm[local * 128 + c * 8 + j * 2];      // LDS broadcast
                u64 n = mm[local * 128 + c * 8 + j * 2 + 1];  // LDS broadcast
                u64 a = am[(c * 4 + j) * 64 + lane];
                z += __builtin_popcountll(a & p) - __builtin_popcountll(a & n);
            }
        }
        u64 fz = __ballot(z >= THETA);
        if (lane == 0) ballots[r0 + local] = fz;
    }
}

// ---------------------------------------------------------------------------
// Transpose: ballots[h*2+s] (bit b = batch) -> f[h] = OR segs (batch-major)
// + next-layer act words in the interleaved convention. grid: 16 x 256.
// ---------------------------------------------------------------------------
__global__ void transpose_kernel(const u64* __restrict__ ballots,
                                 u64* __restrict__ f,
                                 u64* __restrict__ actp) {
    __shared__ u64 lds[256];
    int c = blockIdx.x;
    int tid = threadIdx.x;
    int h = c * 256 + tid;
    u64 fh = ballots[2 * h] | ballots[2 * h + 1];
    f[h] = fh;
    lds[tid] = fh;
    __syncthreads();
    int j = tid >> 6, b = tid & 63;
    u64 word = 0;
    #pragma unroll 8
    for (int i = 0; i < 64; i++)
        word |= ((lds[4 * i + j] >> b) & 1ULL) << i;
    actp[(c * 4 + j) * 64 + b] = word;
}

// ---------------------------------------------------------------------------
// Output: out[b,c] = sum_l sum_h fired_l[b,h] * outW[l,h,c]. lane = batch.
// grid: 480 blocks x 256 thr.
// ---------------------------------------------------------------------------
__global__ void output_kernel(const float* __restrict__ outW,
                              const u64* __restrict__ f,
                              float* __restrict__ out) {
    int tid = threadIdx.x;
    int lane = tid & 63;
    int wid = blockIdx.x * 4 + (tid >> 6);   // 0..1919
    int l = wid / (NCLS * 64);
    int rem = wid % (NCLS * 64);
    int c = rem / 64;
    int chunk = rem % 64;
    const u64* fl = f + l * H_SZ;
    int h0 = chunk * 64;
    float acc = 0.0f;
    #pragma unroll 8
    for (int h = h0; h < h0 + 64; h++) {
        float wv = outW[((size_t)(l * H_SZ + h)) * NCLS + c];
        u64 ball = fl[h];
        if ((ball >> lane) & 1ULL) acc += wv;
    }
    atomicAdd(&out[lane * NCLS + c], acc);
}

// ---------------------------------------------------------------------------
extern "C" void kernel_launch(void* const* d_in, const int* in_sizes, int n_in,
                              void* d_out, int out_size, void* d_ws, size_t ws_size,
                              hipStream_t stream) {
    const float* x    = (const float*)d_in[0];
    const float* W0   = (const float*)d_in[1];
    const float* W1   = (const float*)d_in[2];
    const float* W2   = (const float*)d_in[3];
    const float* outW = (const float*)d_in[4];
    float* out = (float*)d_out;

    // workspace layout (u64-aligned)
    char* ws = (char*)d_ws;
    u64* actp0   = (u64*)(ws);                    // 2048 u64  = 16 KB
    u64* actp1   = (u64*)(ws + 16384);            // 4096 u64  = 32 KB
    u64* actp2   = (u64*)(ws + 49152);            // 4096 u64  = 32 KB
    u64* ballots = (u64*)(ws + 81920);            // 8192 u64  = 64 KB
    u64* f       = (u64*)(ws + 147456);           // 3*4096 u64 = 96 KB
    u64* scratch = (u64*)(ws + 245760);           // dummy actp for last transpose
    u64* mask1   = (u64*)(ws + (4u  << 20));      // 1 Mi u64 = 8 MB
    u64* mask2   = (u64*)(ws + (16u << 20));      // 1 Mi u64 = 8 MB

    hipMemsetAsync(d_out, 0, (size_t)out_size * sizeof(float), stream);

    encode_kernel<<<8, 256, 0, stream>>>(x, actp0);

    // one parallel phase streams ALL 320 MB (layer0 fused + W1/W2 -> masks)
    stream_kernel<<<2560, 256, 0, stream>>>(W0, W1, W2, actp0, ballots, mask1, mask2);

    transpose_kernel<<<16, 256, 0, stream>>>(ballots, f + 0 * H_SZ, actp1);
    mask_layer_kernel<<<512, 256, 0, stream>>>(mask1, actp1, ballots);

    transpose_kernel<<<16, 256, 0, stream>>>(ballots, f + 1 * H_SZ, actp2);
    mask_layer_kernel<<<512, 256, 0, stream>>>(mask2, actp2, ballots);

    transpose_kernel<<<16, 256, 0, stream>>>(ballots, f + 2 * H_SZ, scratch);

    output_kernel<<<480, 256, 0, stream>>>(outW, f, out);
}